// Round 1
// baseline (128.319 us; speedup 1.0000x reference)
//
#include <hip/hip_runtime.h>

#define BATCH 8192
#define NF 1024
#define NS 50000
#define MOM 0.2f

// For each batch index i: head[i] = 1 iff no j<i has the same label;
// nxt[i] = smallest j>i with the same label, else -1.
__global__ void build_chains(const int* __restrict__ labels,
                             int* __restrict__ head, int* __restrict__ nxt) {
    const int i = blockIdx.x;
    const int y = labels[i];
    int earlier = 0;
    int nx = 0x7fffffff;
    for (int j = threadIdx.x; j < BATCH; j += blockDim.x) {
        if (j == i) continue;
        if (labels[j] == y) {
            if (j < i) earlier = 1;
            else nx = min(nx, j);
        }
    }
    // reduce across the block (256 threads = 4 waves of 64)
    for (int off = 32; off; off >>= 1) {
        earlier |= __shfl_xor(earlier, off, 64);
        nx = min(nx, __shfl_xor(nx, off, 64));
    }
    __shared__ int s_e[4], s_n[4];
    const int tid = threadIdx.x;
    if ((tid & 63) == 0) { s_e[tid >> 6] = earlier; s_n[tid >> 6] = nx; }
    __syncthreads();
    if (tid == 0) {
        int e = s_e[0] | s_e[1] | s_e[2] | s_e[3];
        int n = min(min(s_n[0], s_n[1]), min(s_n[2], s_n[3]));
        head[i] = !e;
        nxt[i]  = (n == 0x7fffffff) ? -1 : n;
    }
}

// One block (256 threads, float4 per thread = 1024 floats) per chain head.
// Walk the chain in batch order keeping v in registers; write the final row.
__global__ void apply_chains(const float* __restrict__ f_out,
                             const float* __restrict__ features,
                             const int* __restrict__ labels,
                             const int* __restrict__ head,
                             const int* __restrict__ nxt,
                             float* __restrict__ out) {
    const int i = blockIdx.x;
    if (!head[i]) return;
    const int y = labels[i];
    const int tid = threadIdx.x;

    float4 v = reinterpret_cast<const float4*>(features + (size_t)y * NF)[tid];

    __shared__ float s_part[4];
    int j = i;
    const float m = MOM, om = 1.0f - MOM;
    while (j >= 0) {
        float4 x = reinterpret_cast<const float4*>(f_out + (size_t)j * NF)[tid];
        v.x = m * v.x + om * x.x;
        v.y = m * v.y + om * x.y;
        v.z = m * v.z + om * x.z;
        v.w = m * v.w + om * x.w;
        float s = v.x * v.x + v.y * v.y + v.z * v.z + v.w * v.w;
        for (int off = 32; off; off >>= 1) s += __shfl_xor(s, off, 64);
        if ((tid & 63) == 0) s_part[tid >> 6] = s;
        __syncthreads();
        const float tot = s_part[0] + s_part[1] + s_part[2] + s_part[3];
        __syncthreads();  // protect s_part before next iteration's write
        const float inv = 1.0f / sqrtf(tot);
        v.x *= inv; v.y *= inv; v.z *= inv; v.w *= inv;
        j = nxt[j];
    }
    reinterpret_cast<float4*>(out + (size_t)y * NF)[tid] = v;
}

extern "C" void kernel_launch(void* const* d_in, const int* in_sizes, int n_in,
                              void* d_out, int out_size, void* d_ws, size_t ws_size,
                              hipStream_t stream) {
    const float* f_out    = (const float*)d_in[0];
    const float* features = (const float*)d_in[1];
    const int*   labels   = (const int*)d_in[2];
    float* out = (float*)d_out;

    int* head = (int*)d_ws;
    int* nxt  = head + BATCH;

    // 1. bank starts as a copy of features
    hipMemcpyAsync(out, features, (size_t)NS * NF * sizeof(float),
                   hipMemcpyDeviceToDevice, stream);

    // 2. per-label ordered chains
    build_chains<<<BATCH, 256, 0, stream>>>(labels, head, nxt);

    // 3. apply momentum+normalize updates along each chain
    apply_chains<<<BATCH, 256, 0, stream>>>(f_out, features, labels, head, nxt, out);
}

// Round 2
// 117.541 us; speedup vs baseline: 1.0917x; 1.0917x over previous
//
#include <hip/hip_runtime.h>

#define BATCH 8192
#define NF 1024
#define NS 50000
#define MOM 0.2f

// rowhead[y] = batch index of the FIRST occurrence of label y, or -1.
__global__ void init_rowhead(int* __restrict__ rowhead) {
    const int i = blockIdx.x * blockDim.x + threadIdx.x;
    if (i < NS) rowhead[i] = -1;
}

// For each batch index i: nxt[i] = smallest j>i with same label, else -1.
// If i is the first occurrence of its label, record rowhead[label] = i.
__global__ void build_chains(const int* __restrict__ labels,
                             int* __restrict__ rowhead, int* __restrict__ nxt) {
    const int i = blockIdx.x;
    const int y = labels[i];
    int earlier = 0;
    int nx = 0x7fffffff;
    for (int j = threadIdx.x; j < BATCH; j += blockDim.x) {
        if (j == i) continue;
        if (labels[j] == y) {
            if (j < i) earlier = 1;
            else nx = min(nx, j);
        }
    }
    for (int off = 32; off; off >>= 1) {
        earlier |= __shfl_xor(earlier, off, 64);
        nx = min(nx, __shfl_xor(nx, off, 64));
    }
    __shared__ int s_e[4], s_n[4];
    const int tid = threadIdx.x;
    if ((tid & 63) == 0) { s_e[tid >> 6] = earlier; s_n[tid >> 6] = nx; }
    __syncthreads();
    if (tid == 0) {
        const int e = s_e[0] | s_e[1] | s_e[2] | s_e[3];
        const int n = min(min(s_n[0], s_n[1]), min(s_n[2], s_n[3]));
        nxt[i] = (n == 0x7fffffff) ? -1 : n;
        if (!e) rowhead[y] = i;   // exactly one head per label -> no race
    }
}

// One block per bank row y (256 threads x float4 = 1024 floats in registers).
// Untouched rows: straight copy. Touched rows: walk the duplicate chain,
// momentum-blend + block-reduced L2 normalize each step, write once.
__global__ void fused_bank(const float* __restrict__ f_out,
                           const float* __restrict__ features,
                           const int* __restrict__ rowhead,
                           const int* __restrict__ nxt,
                           float* __restrict__ out) {
    const int y = blockIdx.x;
    const int tid = threadIdx.x;

    float4 v = reinterpret_cast<const float4*>(features + (size_t)y * NF)[tid];

    const int h = rowhead[y];          // block-uniform
    if (h >= 0) {
        __shared__ float s_part[4];
        const float m = MOM, om = 1.0f - MOM;
        int j = h;
        while (j >= 0) {
            const float4 x = reinterpret_cast<const float4*>(f_out + (size_t)j * NF)[tid];
            v.x = m * v.x + om * x.x;
            v.y = m * v.y + om * x.y;
            v.z = m * v.z + om * x.z;
            v.w = m * v.w + om * x.w;
            float s = v.x * v.x + v.y * v.y + v.z * v.z + v.w * v.w;
            for (int off = 32; off; off >>= 1) s += __shfl_xor(s, off, 64);
            if ((tid & 63) == 0) s_part[tid >> 6] = s;
            __syncthreads();
            const float tot = s_part[0] + s_part[1] + s_part[2] + s_part[3];
            __syncthreads();  // protect s_part before next iteration overwrites
            const float inv = 1.0f / sqrtf(tot);
            v.x *= inv; v.y *= inv; v.z *= inv; v.w *= inv;
            j = nxt[j];
        }
    }
    reinterpret_cast<float4*>(out + (size_t)y * NF)[tid] = v;
}

extern "C" void kernel_launch(void* const* d_in, const int* in_sizes, int n_in,
                              void* d_out, int out_size, void* d_ws, size_t ws_size,
                              hipStream_t stream) {
    const float* f_out    = (const float*)d_in[0];
    const float* features = (const float*)d_in[1];
    const int*   labels   = (const int*)d_in[2];
    float* out = (float*)d_out;

    int* rowhead = (int*)d_ws;          // NS ints
    int* nxt     = rowhead + NS;        // BATCH ints

    init_rowhead<<<(NS + 255) / 256, 256, 0, stream>>>(rowhead);
    build_chains<<<BATCH, 256, 0, stream>>>(labels, rowhead, nxt);
    fused_bank<<<NS, 256, 0, stream>>>(f_out, features, rowhead, nxt, out);
}